// Round 13
// baseline (430.873 us; speedup 1.0000x reference)
//
#include <hip/hip_runtime.h>

#define IN_C 128
#define HID 96
#define OUT_C 64
#define W0C 288   // HID*3  (BN width)
#define W1C 192   // OUT_C*3
#define CAP 5120  // per-bucket LDS sort capacity (mean 4096, sigma 64 -> +16 sigma)

typedef __bf16 bf16x8v __attribute__((ext_vector_type(8)));
typedef float  f32x4v  __attribute__((ext_vector_type(4)));

// ---------------- graph preprocessing ----------------

__global__ void k_zero(int* __restrict__ p, int n) {
    int i = blockIdx.x * blockDim.x + threadIdx.x;
    if (i < n) p[i] = 0;
}

// per-dest degree + (dest-bucket, src-bucket) histogram in one pass
__global__ void k_count2(const int* __restrict__ row, const int* __restrict__ col,
                         int* __restrict__ counts, int* __restrict__ dbsb_cnt,
                         int nb, int e) {
    int i = blockIdx.x * blockDim.x + threadIdx.x;
    if (i >= e) return;
    int c = col[i], r = row[i];
    atomicAdd(&counts[c], 1);
    atomicAdd(&dbsb_cnt[(c >> 8) * nb + (r >> 8)], 1);
}

// block sums for bucket scan + dinv (fused: one pass over counts)
__global__ void k_block_sum(const int* __restrict__ counts, int* __restrict__ bsums,
                            float* __restrict__ dinv, int n) {
    __shared__ int s[256];
    int i = blockIdx.x * 256 + threadIdx.x;
    int v = (i < n) ? counts[i] : 0;
    if (i < n) dinv[i] = rsqrtf((float)(v + 1));
    s[threadIdx.x] = v;
    __syncthreads();
    for (int off = 128; off > 0; off >>= 1) {
        if (threadIdx.x < (unsigned)off) s[threadIdx.x] += s[threadIdx.x + off];
        __syncthreads();
    }
    if (threadIdx.x == 0) bsums[blockIdx.x] = s[0];
}

__global__ void k_scan_bsums(int* __restrict__ bsums, int nb) {
    __shared__ int s[256];
    int v = ((int)threadIdx.x < nb) ? bsums[threadIdx.x] : 0;
    s[threadIdx.x] = v;
    __syncthreads();
    for (int off = 1; off < 256; off <<= 1) {
        int t = ((int)threadIdx.x >= off) ? s[threadIdx.x - off] : 0;
        __syncthreads();
        s[threadIdx.x] += t;
        __syncthreads();
    }
    if ((int)threadIdx.x < nb) bsums[threadIdx.x] = s[threadIdx.x] - v;  // exclusive
}

__global__ void k_row_ptr(const int* __restrict__ counts, const int* __restrict__ boffs,
                          int* __restrict__ row_ptr, int n) {
    __shared__ int s[256];
    int i = blockIdx.x * 256 + threadIdx.x;
    int v = (i < n) ? counts[i] : 0;
    s[threadIdx.x] = v;
    __syncthreads();
    for (int off = 1; off < 256; off <<= 1) {
        int t = ((int)threadIdx.x >= off) ? s[threadIdx.x - off] : 0;
        __syncthreads();
        s[threadIdx.x] += t;
        __syncthreads();
    }
    if (i < n) {
        row_ptr[i] = boffs[blockIdx.x] + s[threadIdx.x] - v;
        if (i == n - 1) row_ptr[n] = boffs[blockIdx.x] + s[threadIdx.x];
    }
}

// exclusive scan of each dest-bucket's src-bucket counts (one block per db)
__global__ void k_scan_dbsb(const int* __restrict__ cnt, int* __restrict__ ofs, int nb) {
    __shared__ int s[256];
    int db = blockIdx.x;
    int t = threadIdx.x;
    int v = (t < nb) ? cnt[db * nb + t] : 0;
    s[t] = v;
    __syncthreads();
    for (int o = 1; o < 256; o <<= 1) {
        int u = (t >= o) ? s[t - o] : 0;
        __syncthreads();
        s[t] += u;
        __syncthreads();
    }
    if (t < nb) ofs[db * nb + t] = s[t] - v;  // exclusive
}

// scatter edges into (dest-bucket, src-bucket)-ordered regions: within each dest
// bucket, edges land grouped by ascending src bucket -> the final CSR lists are
// approximately src-sorted, so concurrent SpMM waves sweep src-space in a band.
__global__ void k_scatter_db(const int* __restrict__ row, const int* __restrict__ col,
                             const int* __restrict__ row_ptr, const int* __restrict__ dbsb_ofs,
                             int* __restrict__ dbsb_cur, int2* __restrict__ binned,
                             int nb, int e) {
    int i = blockIdx.x * blockDim.x + threadIdx.x;
    if (i >= e) return;
    int r = row[i], c = col[i];
    int db = c >> 8, sb = r >> 8;
    int cell = db * nb + sb;
    int pos = row_ptr[db << 8] + dbsb_ofs[cell] + atomicAdd(&dbsb_cur[cell], 1);
    binned[pos] = make_int2(r, c);
}

// one block per dest bucket: exact per-dest offsets via LDS ranks; t-ordered walk
// preserves the src-bucket ordering within each dest's list.
__global__ __launch_bounds__(256) void k_bucket_sort(
        const int2* __restrict__ binned, const int* __restrict__ row_ptr,
        const float* __restrict__ dinv,
        int* __restrict__ csr_src, float* __restrict__ csr_w, int n) {
    __shared__ int   s_src[CAP];
    __shared__ float s_w[CAP];
    __shared__ int   s_ofs[256];
    __shared__ int   lcur[256];
    int tid = threadIdx.x;
    int node0 = blockIdx.x << 8;
    int nodeEnd = min(node0 + 256, n);
    int base = row_ptr[node0];
    int end  = row_ptr[nodeEnd];
    int cnt  = end - base;
    {
        int node = node0 + tid;
        s_ofs[tid] = (node < n) ? (row_ptr[node] - base) : cnt;
        lcur[tid] = 0;
    }
    __syncthreads();
    for (int t = tid; t < cnt; t += 256) {
        int2 rc = binned[base + t];
        int local = rc.y - node0;
        int pos = s_ofs[local] + atomicAdd(&lcur[local], 1);
        if (pos < CAP) {
            s_src[pos] = rc.x;
            s_w[pos] = dinv[rc.x] * dinv[rc.y];
        }
    }
    __syncthreads();
    for (int t = tid; t < cnt; t += 256) {
        csr_src[base + t] = s_src[t];
        csr_w[base + t]   = s_w[t];
    }
}

// ---------------- dtype prep ----------------

__global__ void k_cvt_bf16(const float* __restrict__ src, __bf16* __restrict__ dst, int n8) {
    int i = blockIdx.x * blockDim.x + threadIdx.x;
    if (i >= n8) return;
    bf16x8v o;
#pragma unroll
    for (int q = 0; q < 8; q++) o[q] = (__bf16)src[i * 8 + q];
    *(bf16x8v*)(dst + (size_t)i * 8) = o;
}

// all three weight transposes in one launch: dst[j][n][k] = (bf16) src[j][k][n]
__global__ void k_transpose_all(const float* __restrict__ W0, const float* __restrict__ W1,
                                const float* __restrict__ Wf,
                                __bf16* __restrict__ w0t, __bf16* __restrict__ w1t,
                                __bf16* __restrict__ wft) {
    const int T0 = 3 * IN_C * HID;    // 36864
    const int T1 = 3 * W0C * OUT_C;   // 55296
    const int T2 = W1C * OUT_C;       // 12288
    int i = blockIdx.x * blockDim.x + threadIdx.x;
    if (i < T0) {
        int kn = IN_C * HID;
        int j = i / kn, r = i % kn;
        int k = r / HID, nn = r % HID;
        w0t[(size_t)j * kn + (size_t)nn * IN_C + k] = (__bf16)W0[i];
    } else if (i < T0 + T1) {
        int ii = i - T0;
        int kn = W0C * OUT_C;
        int j = ii / kn, r = ii % kn;
        int k = r / OUT_C, nn = r % OUT_C;
        w1t[(size_t)j * kn + (size_t)nn * W0C + k] = (__bf16)W1[ii];
    } else if (i < T0 + T1 + T2) {
        int ii = i - T0 - T1;
        int k = ii / OUT_C, nn = ii % OUT_C;
        wft[(size_t)nn * W1C + k] = (__bf16)Wf[ii];
    }
}

__global__ void k_bn_prep(const float* __restrict__ gamma, const float* __restrict__ beta,
                          const float* __restrict__ mean, const float* __restrict__ var,
                          float* __restrict__ scale, float* __restrict__ shift, int w) {
    int i = blockIdx.x * blockDim.x + threadIdx.x;
    if (i < w) {
        float s = gamma[i] * rsqrtf(var[i] + 1e-5f);
        scale[i] = s;
        shift[i] = beta[i] - mean[i] * s;
    }
}

// ---------------- MFMA GEMMs (hop j = blockIdx.y — split beats fusion, R6/R12) ----
// A-frag: m = lane&15, k = quad*8+j ; B-frag: n = lane&15, k = quad*8+j (WT = (N,K))
// D: col = lane&15, row = quad*4 + reg. Epilogues repack D through padded LDS tiles
// so global stores are coalesced vector stores.

// layer 0: xb (M,128) @ W0[j]; j0: BN+ReLU -> h[:,0:96] (ld 288); j1/j2 -> t12 (ld 192)
__global__ __launch_bounds__(256) void k_mf_l0(
        const __bf16* __restrict__ xb, const __bf16* __restrict__ w0t /* (3,96,128) */,
        const float* __restrict__ bias /* (3,96) */,
        __bf16* __restrict__ h, __bf16* __restrict__ t12,
        const float* __restrict__ scale, const float* __restrict__ shift, int M) {
    const int RS = 104;
    __shared__ __bf16 tile[64 * RS];
    int tid = threadIdx.x;
    int wave = tid >> 6, lane = tid & 63;
    int ln = lane & 15, quad = lane >> 4;
    int j = blockIdx.y;
    int rowBase = blockIdx.x * 64;
    int waveRow = wave * 16;
    const __bf16* wjt = w0t + (size_t)j * HID * IN_C;
    f32x4v acc[6];
#pragma unroll
    for (int t = 0; t < 6; t++) acc[t] = (f32x4v){0.f, 0.f, 0.f, 0.f};
    const __bf16* arow = xb + (size_t)(rowBase + waveRow + ln) * IN_C + quad * 8;
#pragma unroll
    for (int k = 0; k < 4; k++) {
        bf16x8v a = *(const bf16x8v*)(arow + k * 32);
#pragma unroll
        for (int c = 0; c < 6; c++) {
            bf16x8v b = *(const bf16x8v*)(wjt + (size_t)(c * 16 + ln) * IN_C + k * 32 + quad * 8);
            acc[c] = __builtin_amdgcn_mfma_f32_16x16x32_bf16(a, b, acc[c], 0, 0, 0);
        }
    }
    const float* bj = bias + j * HID;
    bool bn = (j == 0);
#pragma unroll
    for (int r = 0; r < 4; r++) {
        int lr = waveRow + quad * 4 + r;
#pragma unroll
        for (int c = 0; c < 6; c++) {
            int col = c * 16 + ln;
            float v = acc[c][r] + bj[col];
            if (bn) v = fmaxf(v * scale[col] + shift[col], 0.f);
            tile[lr * RS + col] = (__bf16)v;
        }
    }
    __syncthreads();
    __bf16* dst; int ld, c0;
    if (j == 0) { dst = h;   ld = W0C; c0 = 0; }
    else        { dst = t12; ld = 192; c0 = (j - 1) * 96; }
#pragma unroll
    for (int s = 0; s < 3; s++) {
        int idx = tid + s * 256;          // 64 rows * 12 chunks
        int r = idx / 12, c8 = idx % 12;
        int grow = rowBase + r;
        if (grow < M)
            *(bf16x8v*)(dst + (size_t)grow * ld + c0 + c8 * 8) =
                *(const bf16x8v*)(tile + r * RS + c8 * 8);
    }
}

// layer 1 (hop-split, R10 form): h (M,288) @ W1[j]; j0 -> g[:,0:64]; j1/j2 -> u12
__global__ __launch_bounds__(256) void k_mf_l1(
        const __bf16* __restrict__ hb, const __bf16* __restrict__ w1t /* (3,64,288) */,
        const float* __restrict__ bias /* (3,64) */,
        __bf16* __restrict__ g, __bf16* __restrict__ u12, int M) {
    const int RS = 72;
    __shared__ __bf16 tile[64 * RS];
    int tid = threadIdx.x;
    int wave = tid >> 6, lane = tid & 63;
    int ln = lane & 15, quad = lane >> 4;
    int j = blockIdx.y;
    int rowBase = blockIdx.x * 64;
    int waveRow = wave * 16;
    const __bf16* wjt = w1t + (size_t)j * OUT_C * W0C;
    f32x4v acc[4];
#pragma unroll
    for (int t = 0; t < 4; t++) acc[t] = (f32x4v){0.f, 0.f, 0.f, 0.f};
    const __bf16* arow = hb + (size_t)(rowBase + waveRow + ln) * W0C + quad * 8;
#pragma unroll
    for (int k = 0; k < 9; k++) {
        bf16x8v a = *(const bf16x8v*)(arow + k * 32);
#pragma unroll
        for (int c = 0; c < 4; c++) {
            bf16x8v b = *(const bf16x8v*)(wjt + (size_t)(c * 16 + ln) * W0C + k * 32 + quad * 8);
            acc[c] = __builtin_amdgcn_mfma_f32_16x16x32_bf16(a, b, acc[c], 0, 0, 0);
        }
    }
    const float* bj = bias + j * OUT_C;
#pragma unroll
    for (int r = 0; r < 4; r++) {
        int lr = waveRow + quad * 4 + r;
#pragma unroll
        for (int c = 0; c < 4; c++) {
            int col = c * 16 + ln;
            tile[lr * RS + col] = (__bf16)(acc[c][r] + bj[col]);
        }
    }
    __syncthreads();
    __bf16* dst; int ld, c0;
    if (j == 0) { dst = g;   ld = W1C; c0 = 0; }
    else        { dst = u12; ld = 128; c0 = (j - 1) * 64; }
#pragma unroll
    for (int s = 0; s < 2; s++) {
        int idx = tid + s * 256;          // 64 rows * 8 chunks
        int r = idx / 8, c8 = idx % 8;
        int grow = rowBase + r;
        if (grow < M)
            *(bf16x8v*)(dst + (size_t)grow * ld + c0 + c8 * 8) =
                *(const bf16x8v*)(tile + r * RS + c8 * 8);
    }
}

// final: g (M,192) @ Wf -> out fp32 (M,64)
__global__ __launch_bounds__(256) void k_mf_fin(
        const __bf16* __restrict__ gb, const __bf16* __restrict__ wft /* (64,192) */,
        const float* __restrict__ bias, float* __restrict__ out, int M) {
    const int RS = 68;
    __shared__ float tile[64 * RS];
    int tid = threadIdx.x;
    int wave = tid >> 6, lane = tid & 63;
    int ln = lane & 15, quad = lane >> 4;
    int rowBase = blockIdx.x * 64;
    int waveRow = wave * 16;
    f32x4v acc[4];
#pragma unroll
    for (int t = 0; t < 4; t++) acc[t] = (f32x4v){0.f, 0.f, 0.f, 0.f};
    const __bf16* arow = gb + (size_t)(rowBase + waveRow + ln) * W1C + quad * 8;
#pragma unroll
    for (int k = 0; k < 6; k++) {
        bf16x8v a = *(const bf16x8v*)(arow + k * 32);
#pragma unroll
        for (int c = 0; c < 4; c++) {
            bf16x8v b = *(const bf16x8v*)(wft + (size_t)(c * 16 + ln) * W1C + k * 32 + quad * 8);
            acc[c] = __builtin_amdgcn_mfma_f32_16x16x32_bf16(a, b, acc[c], 0, 0, 0);
        }
    }
#pragma unroll
    for (int r = 0; r < 4; r++) {
        int lr = waveRow + quad * 4 + r;
#pragma unroll
        for (int c = 0; c < 4; c++) {
            int col = c * 16 + ln;
            tile[lr * RS + col] = acc[c][r] + bias[col];
        }
    }
    __syncthreads();
#pragma unroll
    for (int s = 0; s < 4; s++) {
        int idx = tid + s * 256;          // 64 rows * 16 float4-chunks
        int r = idx / 16, c4 = idx % 16;
        int grow = rowBase + r;
        if (grow < M)
            *(float4*)(out + (size_t)grow * OUT_C + c4 * 4) =
                *(const float4*)(tile + r * RS + c4 * 4);
    }
}

// ---------------- SpMM bf16 (CSR gather, no atomics, 4x-unrolled MLP) -------------
// (4x is the measured optimum: 8x costs occupancy and regresses — R11)
template <int C8, int NPB, bool BNRELU>
__global__ void k_spmm(const __bf16* __restrict__ xin, int ldx,
                       __bf16* __restrict__ xout, int ldo,
                       const int* __restrict__ row_ptr, const int* __restrict__ counts,
                       const int* __restrict__ csr_src, const float* __restrict__ csr_w,
                       const float* __restrict__ dinv, int n,
                       const float* __restrict__ scale, const float* __restrict__ shift,
                       int chan0) {
    int c8 = threadIdx.x % C8;
    int nl = threadIdx.x / C8;
    int node = blockIdx.x * NPB + nl;
    if (node >= n) return;
    float di = dinv[node];
    float lw = di * di;
    float acc[8];
    {
        bf16x8v v = *(const bf16x8v*)(xin + (size_t)node * ldx + c8 * 8);
#pragma unroll
        for (int q = 0; q < 8; q++) acc[q] = lw * (float)v[q];
    }
    int start = row_ptr[node];
    int cnt = counts[node];
    int k = 0;
    for (; k + 4 <= cnt; k += 4) {
        int s0 = csr_src[start + k + 0], s1 = csr_src[start + k + 1];
        int s2 = csr_src[start + k + 2], s3 = csr_src[start + k + 3];
        float w0 = csr_w[start + k + 0], w1 = csr_w[start + k + 1];
        float w2 = csr_w[start + k + 2], w3 = csr_w[start + k + 3];
        bf16x8v v0 = *(const bf16x8v*)(xin + (size_t)s0 * ldx + c8 * 8);
        bf16x8v v1 = *(const bf16x8v*)(xin + (size_t)s1 * ldx + c8 * 8);
        bf16x8v v2 = *(const bf16x8v*)(xin + (size_t)s2 * ldx + c8 * 8);
        bf16x8v v3 = *(const bf16x8v*)(xin + (size_t)s3 * ldx + c8 * 8);
#pragma unroll
        for (int q = 0; q < 8; q++)
            acc[q] += w0 * (float)v0[q] + w1 * (float)v1[q] +
                      w2 * (float)v2[q] + w3 * (float)v3[q];
    }
    for (; k < cnt; k++) {
        int src = csr_src[start + k];
        float w = csr_w[start + k];
        bf16x8v xv = *(const bf16x8v*)(xin + (size_t)src * ldx + c8 * 8);
#pragma unroll
        for (int q = 0; q < 8; q++) acc[q] += w * (float)xv[q];
    }
    bf16x8v o;
#pragma unroll
    for (int q = 0; q < 8; q++) {
        float v = acc[q];
        if (BNRELU) {
            int ch = chan0 + c8 * 8 + q;
            v = fmaxf(v * scale[ch] + shift[ch], 0.f);
        }
        o[q] = (__bf16)v;
    }
    *(bf16x8v*)(xout + (size_t)node * ldo + c8 * 8) = o;
}

template <int C8, int SPLIT, int NPB, bool BNA, bool BNB>
__global__ void k_spmm2(const __bf16* __restrict__ xin, int ldx,
                        __bf16* __restrict__ dstA, int ldA, int chanA,
                        __bf16* __restrict__ dstB, int ldB, int chanB,
                        const int* __restrict__ row_ptr, const int* __restrict__ counts,
                        const int* __restrict__ csr_src, const float* __restrict__ csr_w,
                        const float* __restrict__ dinv, int n,
                        const float* __restrict__ scale, const float* __restrict__ shift) {
    int c8 = threadIdx.x % C8;
    int nl = threadIdx.x / C8;
    int node = blockIdx.x * NPB + nl;
    if (node >= n) return;
    float di = dinv[node];
    float lw = di * di;
    float acc[8];
    {
        bf16x8v v = *(const bf16x8v*)(xin + (size_t)node * ldx + c8 * 8);
#pragma unroll
        for (int q = 0; q < 8; q++) acc[q] = lw * (float)v[q];
    }
    int start = row_ptr[node];
    int cnt = counts[node];
    int k = 0;
    for (; k + 4 <= cnt; k += 4) {
        int s0 = csr_src[start + k + 0], s1 = csr_src[start + k + 1];
        int s2 = csr_src[start + k + 2], s3 = csr_src[start + k + 3];
        float w0 = csr_w[start + k + 0], w1 = csr_w[start + k + 1];
        float w2 = csr_w[start + k + 2], w3 = csr_w[start + k + 3];
        bf16x8v v0 = *(const bf16x8v*)(xin + (size_t)s0 * ldx + c8 * 8);
        bf16x8v v1 = *(const bf16x8v*)(xin + (size_t)s1 * ldx + c8 * 8);
        bf16x8v v2 = *(const bf16x8v*)(xin + (size_t)s2 * ldx + c8 * 8);
        bf16x8v v3 = *(const bf16x8v*)(xin + (size_t)s3 * ldx + c8 * 8);
#pragma unroll
        for (int q = 0; q < 8; q++)
            acc[q] += w0 * (float)v0[q] + w1 * (float)v1[q] +
                      w2 * (float)v2[q] + w3 * (float)v3[q];
    }
    for (; k < cnt; k++) {
        int src = csr_src[start + k];
        float w = csr_w[start + k];
        bf16x8v xv = *(const bf16x8v*)(xin + (size_t)src * ldx + c8 * 8);
#pragma unroll
        for (int q = 0; q < 8; q++) acc[q] += w * (float)xv[q];
    }
    bool isA = c8 < SPLIT;
    __bf16* dst = isA ? dstA : dstB;
    int ld   = isA ? ldA : ldB;
    int lc8  = isA ? c8 : c8 - SPLIT;
    int chan = isA ? chanA : chanB;
    bool bn  = isA ? BNA : BNB;
    bf16x8v o;
#pragma unroll
    for (int q = 0; q < 8; q++) {
        float v = acc[q];
        if (bn) {
            int ch = chan + lc8 * 8 + q;
            v = fmaxf(v * scale[ch] + shift[ch], 0.f);
        }
        o[q] = (__bf16)v;
    }
    *(bf16x8v*)(dst + (size_t)node * ld + lc8 * 8) = o;
}

// ---------------- launch ----------------

extern "C" void kernel_launch(void* const* d_in, const int* in_sizes, int n_in,
                              void* d_out, int out_size, void* d_ws, size_t ws_size,
                              hipStream_t stream) {
    const int n = in_sizes[0] / IN_C;   // 50000
    const int e = in_sizes[1] / 2;      // 800000

    const float* x    = (const float*)d_in[0];
    const int*   ei   = (const int*)d_in[1];
    const float* W0   = (const float*)d_in[2];   // (3,128,96)
    const float* b0   = (const float*)d_in[3];
    const float* W1   = (const float*)d_in[4];   // (3,288,64)
    const float* b1   = (const float*)d_in[5];
    const float* bn_g = (const float*)d_in[6];
    const float* bn_b = (const float*)d_in[7];
    const float* bn_m = (const float*)d_in[8];
    const float* bn_v = (const float*)d_in[9];
    const float* Wf   = (const float*)d_in[10];  // (192,64)
    const float* bf   = (const float*)d_in[11];
    float* out = (float*)d_out;

    const int* e_row = ei;
    const int* e_col = ei + e;

    char* ws = (char*)d_ws;
    size_t off = 0;
    auto alloc = [&](size_t bytes) -> void* {
        void* p = ws + off;
        off += (bytes + 255) & ~(size_t)255;
        return p;
    };
    const int NP = n + 64;           // row padding so GEMM A-frag loads never leave ws
    const int nb = (n + 255) / 256;  // 196 buckets (dest and src)

    // counts[n] + dbsb_cnt[nb*nb] + dbsb_cur[nb*nb] contiguous (zeroed together)
    int*    counts   = (int*)alloc((size_t)(n + 2 * nb * nb) * 4);
    int*    dbsb_cnt = counts + n;
    int*    dbsb_cur = dbsb_cnt + nb * nb;
    int*    dbsb_ofs = (int*)alloc((size_t)nb * nb * 4);
    int*    row_ptr  = (int*)alloc((size_t)(n + 1) * 4);
    int*    bsums    = (int*)alloc(256 * 4);
    float*  dinv     = (float*)alloc((size_t)n * 4);
    int2*   binned   = (int2*)alloc((size_t)e * 8);
    int*    csr_src  = (int*)alloc((size_t)e * 4);
    float*  csr_w    = (float*)alloc((size_t)e * 4);
    float*  bnscale  = (float*)alloc(W0C * 4);
    float*  bnshift  = (float*)alloc(W0C * 4);
    __bf16* xb  = (__bf16*)alloc((size_t)NP * IN_C * 2);
    __bf16* w0t = (__bf16*)alloc((size_t)3 * HID * IN_C * 2);
    __bf16* w1t = (__bf16*)alloc((size_t)3 * OUT_C * W0C * 2);
    __bf16* wft = (__bf16*)alloc((size_t)OUT_C * W1C * 2);
    __bf16* t12 = (__bf16*)alloc((size_t)NP * 192 * 2);  // [t1 | t2] hops 1,2 of layer 0
    __bf16* tp  = (__bf16*)alloc((size_t)NP * HID * 2);
    __bf16* h   = (__bf16*)alloc((size_t)NP * W0C * 2);
    __bf16* g   = (__bf16*)alloc((size_t)NP * W1C * 2);
    __bf16* u12 = t12;  // layer-1 [u1 | u2] (n,128) reuses dead t12
    __bf16* up  = tp;   // (n,64) reuses dead tp

    const int TB = 256;
    int ztotal = n + 2 * nb * nb;

    // --- graph prep (src-bucket-ordered CSR build) ---
    k_zero<<<dim3((ztotal + TB - 1) / TB), dim3(TB), 0, stream>>>(counts, ztotal);
    k_count2<<<dim3((e + TB - 1) / TB), dim3(TB), 0, stream>>>(e_row, e_col, counts,
                                                               dbsb_cnt, nb, e);
    k_block_sum<<<dim3(nb), dim3(256), 0, stream>>>(counts, bsums, dinv, n);
    k_scan_bsums<<<dim3(1), dim3(256), 0, stream>>>(bsums, nb);
    k_row_ptr<<<dim3(nb), dim3(256), 0, stream>>>(counts, bsums, row_ptr, n);
    k_scan_dbsb<<<dim3(nb), dim3(256), 0, stream>>>(dbsb_cnt, dbsb_ofs, nb);
    k_scatter_db<<<dim3((e + TB - 1) / TB), dim3(TB), 0, stream>>>(e_row, e_col, row_ptr,
                                                                   dbsb_ofs, dbsb_cur,
                                                                   binned, nb, e);
    k_bucket_sort<<<dim3(nb), dim3(256), 0, stream>>>(binned, row_ptr, dinv, csr_src, csr_w, n);
    k_bn_prep<<<dim3(2), dim3(256), 0, stream>>>(bn_g, bn_b, bn_m, bn_v, bnscale, bnshift, W0C);

    // --- dtype prep ---
    k_cvt_bf16<<<dim3((n * IN_C / 8 + TB - 1) / TB), dim3(TB), 0, stream>>>(x, xb, n * IN_C / 8);
    int ttotal = 3 * IN_C * HID + 3 * W0C * OUT_C + W1C * OUT_C;  // 104448
    k_transpose_all<<<dim3((ttotal + TB - 1) / TB), dim3(TB), 0, stream>>>(W0, W1, Wf,
                                                                           w0t, w1t, wft);

    dim3 g64x3((n + 63) / 64, 3);
    dim3 g64((n + 63) / 64);

    // --- layer 0 (hop j = blockIdx.y) ---
    k_mf_l0<<<g64x3, dim3(256), 0, stream>>>(xb, w0t, b0, h, t12, bnscale, bnshift, n);

    // merged SpMM @192ch on t12: first 96 -> h[:,96:192] (BN), second 96 -> tp (raw)
    k_spmm2<24, 12, 8, true, false><<<dim3((n + 7) / 8), dim3(192), 0, stream>>>(
        t12, 192, h + HID, W0C, HID, tp, HID, 0,
        row_ptr, counts, csr_src, csr_w, dinv, n, bnscale, bnshift);
    // second hop: tp -> h[:,192:288] (BN)
    k_spmm<12, 16, true><<<dim3((n + 15) / 16), dim3(192), 0, stream>>>(
        tp, HID, h + 2 * HID, W0C, row_ptr, counts, csr_src, csr_w, dinv, n,
        bnscale, bnshift, 2 * HID);

    // --- layer 1 (hop j = blockIdx.y) ---
    k_mf_l1<<<g64x3, dim3(256), 0, stream>>>(h, w1t, b1, g, u12, n);

    // merged SpMM @128ch on u12: first 64 -> g[:,64:128], second 64 -> up
    k_spmm2<16, 8, 16, false, false><<<dim3((n + 15) / 16), dim3(256), 0, stream>>>(
        u12, 128, g + OUT_C, W1C, 0, up, OUT_C, 0,
        row_ptr, counts, csr_src, csr_w, dinv, n, nullptr, nullptr);
    // second hop: up -> g[:,128:192]
    k_spmm<8, 32, false><<<dim3((n + 31) / 32), dim3(256), 0, stream>>>(
        up, OUT_C, g + 2 * OUT_C, W1C, row_ptr, counts, csr_src, csr_w, dinv, n,
        nullptr, nullptr, 0);

    // --- final projection ---
    k_mf_fin<<<g64, dim3(256), 0, stream>>>(g, wft, bf, out, n);
}

// Round 14
// 384.794 us; speedup vs baseline: 1.1197x; 1.1197x over previous
//
#include <hip/hip_runtime.h>

#define IN_C 128
#define HID 96
#define OUT_C 64
#define W0C 288   // HID*3  (BN width)
#define W1C 192   // OUT_C*3
#define CAP 5120  // per-bucket LDS sort capacity (mean 4096, sigma 64 -> +16 sigma)
#define EPB 4096  // edges per binscatter block

typedef __bf16 bf16x8v __attribute__((ext_vector_type(8)));
typedef float  f32x4v  __attribute__((ext_vector_type(4)));

// ---------------- graph preprocessing ----------------

__global__ void k_zero(int* __restrict__ p, int n) {
    int i = blockIdx.x * blockDim.x + threadIdx.x;
    if (i < n) p[i] = 0;
}

__global__ void k_count(const int* __restrict__ col, int* __restrict__ counts, int e) {
    int i = blockIdx.x * blockDim.x + threadIdx.x;
    if (i < e) atomicAdd(&counts[col[i]], 1);
}

// block sums for bucket scan + dinv (fused: one pass over counts)
__global__ void k_block_sum(const int* __restrict__ counts, int* __restrict__ bsums,
                            float* __restrict__ dinv, int n) {
    __shared__ int s[256];
    int i = blockIdx.x * 256 + threadIdx.x;
    int v = (i < n) ? counts[i] : 0;
    if (i < n) dinv[i] = rsqrtf((float)(v + 1));
    s[threadIdx.x] = v;
    __syncthreads();
    for (int off = 128; off > 0; off >>= 1) {
        if (threadIdx.x < (unsigned)off) s[threadIdx.x] += s[threadIdx.x + off];
        __syncthreads();
    }
    if (threadIdx.x == 0) bsums[blockIdx.x] = s[0];
}

__global__ void k_scan_bsums(int* __restrict__ bsums, int nb) {
    __shared__ int s[256];
    int v = ((int)threadIdx.x < nb) ? bsums[threadIdx.x] : 0;
    s[threadIdx.x] = v;
    __syncthreads();
    for (int off = 1; off < 256; off <<= 1) {
        int t = ((int)threadIdx.x >= off) ? s[threadIdx.x - off] : 0;
        __syncthreads();
        s[threadIdx.x] += t;
        __syncthreads();
    }
    if ((int)threadIdx.x < nb) bsums[threadIdx.x] = s[threadIdx.x] - v;  // exclusive
}

__global__ void k_row_ptr(const int* __restrict__ counts, const int* __restrict__ boffs,
                          int* __restrict__ row_ptr, int n) {
    __shared__ int s[256];
    int i = blockIdx.x * 256 + threadIdx.x;
    int v = (i < n) ? counts[i] : 0;
    s[threadIdx.x] = v;
    __syncthreads();
    for (int off = 1; off < 256; off <<= 1) {
        int t = ((int)threadIdx.x >= off) ? s[threadIdx.x - off] : 0;
        __syncthreads();
        s[threadIdx.x] += t;
        __syncthreads();
    }
    if (i < n) {
        row_ptr[i] = boffs[blockIdx.x] + s[threadIdx.x] - v;
        if (i == n - 1) row_ptr[n] = boffs[blockIdx.x] + s[threadIdx.x];
    }
}

// LDS-aggregated dest-bucket scatter: one global atomic per (block,bucket) on
// line-padded cursors (R4 design — cheap, ~10 us).
__global__ __launch_bounds__(256) void k_binscatter(
        const int* __restrict__ row, const int* __restrict__ col,
        const int* __restrict__ row_ptr, int* __restrict__ bcur /* stride 16 */,
        int2* __restrict__ binned, int e) {
    __shared__ int hist[256];
    __shared__ int base[256];
    int tid = threadIdx.x;
    int e0 = blockIdx.x * EPB;
    int cnt = min(EPB, e - e0);
    hist[tid] = 0;
    __syncthreads();
    int rr[16], cc[16], rk[16];
#pragma unroll
    for (int k = 0; k < 16; k++) {
        int idx = tid + k * 256;
        if (idx < cnt) {
            rr[k] = row[e0 + idx];
            cc[k] = col[e0 + idx];
            rk[k] = atomicAdd(&hist[cc[k] >> 8], 1);
        }
    }
    __syncthreads();
    {
        int h = hist[tid];
        if (h > 0) base[tid] = atomicAdd(&bcur[tid * 16], h);
    }
    __syncthreads();
#pragma unroll
    for (int k = 0; k < 16; k++) {
        int idx = tid + k * 256;
        if (idx < cnt) {
            int b = cc[k] >> 8;
            binned[row_ptr[b << 8] + base[b] + rk[k]] = make_int2(rr[k], cc[k]);
        }
    }
}

// One block per dest bucket. Three in-LDS passes:
//  A) histogram edges by SRC bucket;  B) counting-sort edges into src-bucket
//  order (s_src/s_w reused as the edge buffer);  C) dest-rank walk over the
//  src-grouped buffer, writing csr_src/csr_w (scattered 4B within the L2-hot
//  bucket region -> write amp ~1). Result: each dest's edge list is
//  approximately src-ascending, so concurrent SpMM waves sweep src-space in a
//  band (L2-resident) instead of randomly (R13: -40 us on SpMM aggregate).
__global__ __launch_bounds__(256) void k_bucket_sort(
        const int2* __restrict__ binned, const int* __restrict__ row_ptr,
        const float* __restrict__ dinv,
        int* __restrict__ csr_src, float* __restrict__ csr_w, int n) {
    __shared__ int   s_src[CAP];     // pass B/C: src of edge
    __shared__ int   s_col[CAP];     // pass B/C: col of edge
    __shared__ int   s_ofs[256];
    __shared__ int   lcur[256];
    int tid = threadIdx.x;
    int node0 = blockIdx.x << 8;
    int nodeEnd = min(node0 + 256, n);
    int base = row_ptr[node0];
    int end  = row_ptr[nodeEnd];
    int cnt  = end - base;

    // ---- pass A: src-bucket histogram ----
    lcur[tid] = 0;
    __syncthreads();
    for (int t = tid; t < cnt; t += 256) {
        atomicAdd(&lcur[binned[base + t].x >> 8], 1);
    }
    __syncthreads();
    {   // exclusive scan of lcur into lcur (cursor init)
        int v = lcur[tid];
        s_ofs[tid] = v;
        __syncthreads();
        for (int o = 1; o < 256; o <<= 1) {
            int u = (tid >= o) ? s_ofs[tid - o] : 0;
            __syncthreads();
            s_ofs[tid] += u;
            __syncthreads();
        }
        lcur[tid] = s_ofs[tid] - v;
    }
    __syncthreads();
    // ---- pass B: scatter into src-bucket order (LDS) ----
    for (int t = tid; t < cnt; t += 256) {
        int2 rc = binned[base + t];
        int pos = atomicAdd(&lcur[rc.x >> 8], 1);
        if (pos < CAP) {
            s_src[pos] = rc.x;
            s_col[pos] = rc.y;
        }
    }
    __syncthreads();
    // ---- pass C: dest-rank in src order, write csr directly ----
    {
        int node = node0 + tid;
        s_ofs[tid] = (node < n) ? (row_ptr[node] - base) : cnt;
        lcur[tid] = 0;
    }
    __syncthreads();
    int lim = min(cnt, CAP);
    for (int t = tid; t < lim; t += 256) {
        int r = s_src[t], c = s_col[t];
        int local = c - node0;
        int pos = s_ofs[local] + atomicAdd(&lcur[local], 1);
        csr_src[base + pos] = r;
        csr_w[base + pos]   = dinv[r] * dinv[c];
    }
}

// ---------------- dtype prep ----------------

__global__ void k_cvt_bf16(const float* __restrict__ src, __bf16* __restrict__ dst, int n8) {
    int i = blockIdx.x * blockDim.x + threadIdx.x;
    if (i >= n8) return;
    bf16x8v o;
#pragma unroll
    for (int q = 0; q < 8; q++) o[q] = (__bf16)src[i * 8 + q];
    *(bf16x8v*)(dst + (size_t)i * 8) = o;
}

// all three weight transposes in one launch: dst[j][n][k] = (bf16) src[j][k][n]
__global__ void k_transpose_all(const float* __restrict__ W0, const float* __restrict__ W1,
                                const float* __restrict__ Wf,
                                __bf16* __restrict__ w0t, __bf16* __restrict__ w1t,
                                __bf16* __restrict__ wft) {
    const int T0 = 3 * IN_C * HID;    // 36864
    const int T1 = 3 * W0C * OUT_C;   // 55296
    const int T2 = W1C * OUT_C;       // 12288
    int i = blockIdx.x * blockDim.x + threadIdx.x;
    if (i < T0) {
        int kn = IN_C * HID;
        int j = i / kn, r = i % kn;
        int k = r / HID, nn = r % HID;
        w0t[(size_t)j * kn + (size_t)nn * IN_C + k] = (__bf16)W0[i];
    } else if (i < T0 + T1) {
        int ii = i - T0;
        int kn = W0C * OUT_C;
        int j = ii / kn, r = ii % kn;
        int k = r / OUT_C, nn = r % OUT_C;
        w1t[(size_t)j * kn + (size_t)nn * W0C + k] = (__bf16)W1[ii];
    } else if (i < T0 + T1 + T2) {
        int ii = i - T0 - T1;
        int k = ii / OUT_C, nn = ii % OUT_C;
        wft[(size_t)nn * W1C + k] = (__bf16)Wf[ii];
    }
}

__global__ void k_bn_prep(const float* __restrict__ gamma, const float* __restrict__ beta,
                          const float* __restrict__ mean, const float* __restrict__ var,
                          float* __restrict__ scale, float* __restrict__ shift, int w) {
    int i = blockIdx.x * blockDim.x + threadIdx.x;
    if (i < w) {
        float s = gamma[i] * rsqrtf(var[i] + 1e-5f);
        scale[i] = s;
        shift[i] = beta[i] - mean[i] * s;
    }
}

// ---------------- MFMA GEMMs (hop j = blockIdx.y — split beats fusion, R6/R12) ----
// A-frag: m = lane&15, k = quad*8+j ; B-frag: n = lane&15, k = quad*8+j (WT = (N,K))
// D: col = lane&15, row = quad*4 + reg. Epilogues repack D through padded LDS tiles
// so global stores are coalesced vector stores.

// layer 0: xb (M,128) @ W0[j]; j0: BN+ReLU -> h[:,0:96] (ld 288); j1/j2 -> t12 (ld 192)
__global__ __launch_bounds__(256) void k_mf_l0(
        const __bf16* __restrict__ xb, const __bf16* __restrict__ w0t /* (3,96,128) */,
        const float* __restrict__ bias /* (3,96) */,
        __bf16* __restrict__ h, __bf16* __restrict__ t12,
        const float* __restrict__ scale, const float* __restrict__ shift, int M) {
    const int RS = 104;
    __shared__ __bf16 tile[64 * RS];
    int tid = threadIdx.x;
    int wave = tid >> 6, lane = tid & 63;
    int ln = lane & 15, quad = lane >> 4;
    int j = blockIdx.y;
    int rowBase = blockIdx.x * 64;
    int waveRow = wave * 16;
    const __bf16* wjt = w0t + (size_t)j * HID * IN_C;
    f32x4v acc[6];
#pragma unroll
    for (int t = 0; t < 6; t++) acc[t] = (f32x4v){0.f, 0.f, 0.f, 0.f};
    const __bf16* arow = xb + (size_t)(rowBase + waveRow + ln) * IN_C + quad * 8;
#pragma unroll
    for (int k = 0; k < 4; k++) {
        bf16x8v a = *(const bf16x8v*)(arow + k * 32);
#pragma unroll
        for (int c = 0; c < 6; c++) {
            bf16x8v b = *(const bf16x8v*)(wjt + (size_t)(c * 16 + ln) * IN_C + k * 32 + quad * 8);
            acc[c] = __builtin_amdgcn_mfma_f32_16x16x32_bf16(a, b, acc[c], 0, 0, 0);
        }
    }
    const float* bj = bias + j * HID;
    bool bn = (j == 0);
#pragma unroll
    for (int r = 0; r < 4; r++) {
        int lr = waveRow + quad * 4 + r;
#pragma unroll
        for (int c = 0; c < 6; c++) {
            int col = c * 16 + ln;
            float v = acc[c][r] + bj[col];
            if (bn) v = fmaxf(v * scale[col] + shift[col], 0.f);
            tile[lr * RS + col] = (__bf16)v;
        }
    }
    __syncthreads();
    __bf16* dst; int ld, c0;
    if (j == 0) { dst = h;   ld = W0C; c0 = 0; }
    else        { dst = t12; ld = 192; c0 = (j - 1) * 96; }
#pragma unroll
    for (int s = 0; s < 3; s++) {
        int idx = tid + s * 256;          // 64 rows * 12 chunks
        int r = idx / 12, c8 = idx % 12;
        int grow = rowBase + r;
        if (grow < M)
            *(bf16x8v*)(dst + (size_t)grow * ld + c0 + c8 * 8) =
                *(const bf16x8v*)(tile + r * RS + c8 * 8);
    }
}

// layer 1 (hop-split): h (M,288) @ W1[j]; j0 -> g[:,0:64]; j1/j2 -> u12
__global__ __launch_bounds__(256) void k_mf_l1(
        const __bf16* __restrict__ hb, const __bf16* __restrict__ w1t /* (3,64,288) */,
        const float* __restrict__ bias /* (3,64) */,
        __bf16* __restrict__ g, __bf16* __restrict__ u12, int M) {
    const int RS = 72;
    __shared__ __bf16 tile[64 * RS];
    int tid = threadIdx.x;
    int wave = tid >> 6, lane = tid & 63;
    int ln = lane & 15, quad = lane >> 4;
    int j = blockIdx.y;
    int rowBase = blockIdx.x * 64;
    int waveRow = wave * 16;
    const __bf16* wjt = w1t + (size_t)j * OUT_C * W0C;
    f32x4v acc[4];
#pragma unroll
    for (int t = 0; t < 4; t++) acc[t] = (f32x4v){0.f, 0.f, 0.f, 0.f};
    const __bf16* arow = hb + (size_t)(rowBase + waveRow + ln) * W0C + quad * 8;
#pragma unroll
    for (int k = 0; k < 9; k++) {
        bf16x8v a = *(const bf16x8v*)(arow + k * 32);
#pragma unroll
        for (int c = 0; c < 4; c++) {
            bf16x8v b = *(const bf16x8v*)(wjt + (size_t)(c * 16 + ln) * W0C + k * 32 + quad * 8);
            acc[c] = __builtin_amdgcn_mfma_f32_16x16x32_bf16(a, b, acc[c], 0, 0, 0);
        }
    }
    const float* bj = bias + j * OUT_C;
#pragma unroll
    for (int r = 0; r < 4; r++) {
        int lr = waveRow + quad * 4 + r;
#pragma unroll
        for (int c = 0; c < 4; c++) {
            int col = c * 16 + ln;
            tile[lr * RS + col] = (__bf16)(acc[c][r] + bj[col]);
        }
    }
    __syncthreads();
    __bf16* dst; int ld, c0;
    if (j == 0) { dst = g;   ld = W1C; c0 = 0; }
    else        { dst = u12; ld = 128; c0 = (j - 1) * 64; }
#pragma unroll
    for (int s = 0; s < 2; s++) {
        int idx = tid + s * 256;          // 64 rows * 8 chunks
        int r = idx / 8, c8 = idx % 8;
        int grow = rowBase + r;
        if (grow < M)
            *(bf16x8v*)(dst + (size_t)grow * ld + c0 + c8 * 8) =
                *(const bf16x8v*)(tile + r * RS + c8 * 8);
    }
}

// final: g (M,192) @ Wf -> out fp32 (M,64)
__global__ __launch_bounds__(256) void k_mf_fin(
        const __bf16* __restrict__ gb, const __bf16* __restrict__ wft /* (64,192) */,
        const float* __restrict__ bias, float* __restrict__ out, int M) {
    const int RS = 68;
    __shared__ float tile[64 * RS];
    int tid = threadIdx.x;
    int wave = tid >> 6, lane = tid & 63;
    int ln = lane & 15, quad = lane >> 4;
    int rowBase = blockIdx.x * 64;
    int waveRow = wave * 16;
    f32x4v acc[4];
#pragma unroll
    for (int t = 0; t < 4; t++) acc[t] = (f32x4v){0.f, 0.f, 0.f, 0.f};
    const __bf16* arow = gb + (size_t)(rowBase + waveRow + ln) * W1C + quad * 8;
#pragma unroll
    for (int k = 0; k < 6; k++) {
        bf16x8v a = *(const bf16x8v*)(arow + k * 32);
#pragma unroll
        for (int c = 0; c < 4; c++) {
            bf16x8v b = *(const bf16x8v*)(wft + (size_t)(c * 16 + ln) * W1C + k * 32 + quad * 8);
            acc[c] = __builtin_amdgcn_mfma_f32_16x16x32_bf16(a, b, acc[c], 0, 0, 0);
        }
    }
#pragma unroll
    for (int r = 0; r < 4; r++) {
        int lr = waveRow + quad * 4 + r;
#pragma unroll
        for (int c = 0; c < 4; c++) {
            int col = c * 16 + ln;
            tile[lr * RS + col] = acc[c][r] + bias[col];
        }
    }
    __syncthreads();
#pragma unroll
    for (int s = 0; s < 4; s++) {
        int idx = tid + s * 256;          // 64 rows * 16 float4-chunks
        int r = idx / 16, c4 = idx % 16;
        int grow = rowBase + r;
        if (grow < M)
            *(float4*)(out + (size_t)grow * OUT_C + c4 * 4) =
                *(const float4*)(tile + r * RS + c4 * 4);
    }
}

// ---------------- SpMM bf16 (CSR gather, no atomics, 4x-unrolled MLP) -------------
// (4x is the measured optimum: 8x costs occupancy and regresses — R11)
template <int C8, int NPB, bool BNRELU>
__global__ void k_spmm(const __bf16* __restrict__ xin, int ldx,
                       __bf16* __restrict__ xout, int ldo,
                       const int* __restrict__ row_ptr, const int* __restrict__ counts,
                       const int* __restrict__ csr_src, const float* __restrict__ csr_w,
                       const float* __restrict__ dinv, int n,
                       const float* __restrict__ scale, const float* __restrict__ shift,
                       int chan0) {
    int c8 = threadIdx.x % C8;
    int nl = threadIdx.x / C8;
    int node = blockIdx.x * NPB + nl;
    if (node >= n) return;
    float di = dinv[node];
    float lw = di * di;
    float acc[8];
    {
        bf16x8v v = *(const bf16x8v*)(xin + (size_t)node * ldx + c8 * 8);
#pragma unroll
        for (int q = 0; q < 8; q++) acc[q] = lw * (float)v[q];
    }
    int start = row_ptr[node];
    int cnt = counts[node];
    int k = 0;
    for (; k + 4 <= cnt; k += 4) {
        int s0 = csr_src[start + k + 0], s1 = csr_src[start + k + 1];
        int s2 = csr_src[start + k + 2], s3 = csr_src[start + k + 3];
        float w0 = csr_w[start + k + 0], w1 = csr_w[start + k + 1];
        float w2 = csr_w[start + k + 2], w3 = csr_w[start + k + 3];
        bf16x8v v0 = *(const bf16x8v*)(xin + (size_t)s0 * ldx + c8 * 8);
        bf16x8v v1 = *(const bf16x8v*)(xin + (size_t)s1 * ldx + c8 * 8);
        bf16x8v v2 = *(const bf16x8v*)(xin + (size_t)s2 * ldx + c8 * 8);
        bf16x8v v3 = *(const bf16x8v*)(xin + (size_t)s3 * ldx + c8 * 8);
#pragma unroll
        for (int q = 0; q < 8; q++)
            acc[q] += w0 * (float)v0[q] + w1 * (float)v1[q] +
                      w2 * (float)v2[q] + w3 * (float)v3[q];
    }
    for (; k < cnt; k++) {
        int src = csr_src[start + k];
        float w = csr_w[start + k];
        bf16x8v xv = *(const bf16x8v*)(xin + (size_t)src * ldx + c8 * 8);
#pragma unroll
        for (int q = 0; q < 8; q++) acc[q] += w * (float)xv[q];
    }
    bf16x8v o;
#pragma unroll
    for (int q = 0; q < 8; q++) {
        float v = acc[q];
        if (BNRELU) {
            int ch = chan0 + c8 * 8 + q;
            v = fmaxf(v * scale[ch] + shift[ch], 0.f);
        }
        o[q] = (__bf16)v;
    }
    *(bf16x8v*)(xout + (size_t)node * ldo + c8 * 8) = o;
}

template <int C8, int SPLIT, int NPB, bool BNA, bool BNB>
__global__ void k_spmm2(const __bf16* __restrict__ xin, int ldx,
                        __bf16* __restrict__ dstA, int ldA, int chanA,
                        __bf16* __restrict__ dstB, int ldB, int chanB,
                        const int* __restrict__ row_ptr, const int* __restrict__ counts,
                        const int* __restrict__ csr_src, const float* __restrict__ csr_w,
                        const float* __restrict__ dinv, int n,
                        const float* __restrict__ scale, const float* __restrict__ shift) {
    int c8 = threadIdx.x % C8;
    int nl = threadIdx.x / C8;
    int node = blockIdx.x * NPB + nl;
    if (node >= n) return;
    float di = dinv[node];
    float lw = di * di;
    float acc[8];
    {
        bf16x8v v = *(const bf16x8v*)(xin + (size_t)node * ldx + c8 * 8);
#pragma unroll
        for (int q = 0; q < 8; q++) acc[q] = lw * (float)v[q];
    }
    int start = row_ptr[node];
    int cnt = counts[node];
    int k = 0;
    for (; k + 4 <= cnt; k += 4) {
        int s0 = csr_src[start + k + 0], s1 = csr_src[start + k + 1];
        int s2 = csr_src[start + k + 2], s3 = csr_src[start + k + 3];
        float w0 = csr_w[start + k + 0], w1 = csr_w[start + k + 1];
        float w2 = csr_w[start + k + 2], w3 = csr_w[start + k + 3];
        bf16x8v v0 = *(const bf16x8v*)(xin + (size_t)s0 * ldx + c8 * 8);
        bf16x8v v1 = *(const bf16x8v*)(xin + (size_t)s1 * ldx + c8 * 8);
        bf16x8v v2 = *(const bf16x8v*)(xin + (size_t)s2 * ldx + c8 * 8);
        bf16x8v v3 = *(const bf16x8v*)(xin + (size_t)s3 * ldx + c8 * 8);
#pragma unroll
        for (int q = 0; q < 8; q++)
            acc[q] += w0 * (float)v0[q] + w1 * (float)v1[q] +
                      w2 * (float)v2[q] + w3 * (float)v3[q];
    }
    for (; k < cnt; k++) {
        int src = csr_src[start + k];
        float w = csr_w[start + k];
        bf16x8v xv = *(const bf16x8v*)(xin + (size_t)src * ldx + c8 * 8);
#pragma unroll
        for (int q = 0; q < 8; q++) acc[q] += w * (float)xv[q];
    }
    bool isA = c8 < SPLIT;
    __bf16* dst = isA ? dstA : dstB;
    int ld   = isA ? ldA : ldB;
    int lc8  = isA ? c8 : c8 - SPLIT;
    int chan = isA ? chanA : chanB;
    bool bn  = isA ? BNA : BNB;
    bf16x8v o;
#pragma unroll
    for (int q = 0; q < 8; q++) {
        float v = acc[q];
        if (bn) {
            int ch = chan + lc8 * 8 + q;
            v = fmaxf(v * scale[ch] + shift[ch], 0.f);
        }
        o[q] = (__bf16)v;
    }
    *(bf16x8v*)(dst + (size_t)node * ld + lc8 * 8) = o;
}

// ---------------- launch ----------------

extern "C" void kernel_launch(void* const* d_in, const int* in_sizes, int n_in,
                              void* d_out, int out_size, void* d_ws, size_t ws_size,
                              hipStream_t stream) {
    const int n = in_sizes[0] / IN_C;   // 50000
    const int e = in_sizes[1] / 2;      // 800000

    const float* x    = (const float*)d_in[0];
    const int*   ei   = (const int*)d_in[1];
    const float* W0   = (const float*)d_in[2];   // (3,128,96)
    const float* b0   = (const float*)d_in[3];
    const float* W1   = (const float*)d_in[4];   // (3,288,64)
    const float* b1   = (const float*)d_in[5];
    const float* bn_g = (const float*)d_in[6];
    const float* bn_b = (const float*)d_in[7];
    const float* bn_m = (const float*)d_in[8];
    const float* bn_v = (const float*)d_in[9];
    const float* Wf   = (const float*)d_in[10];  // (192,64)
    const float* bf   = (const float*)d_in[11];
    float* out = (float*)d_out;

    const int* e_row = ei;
    const int* e_col = ei + e;

    char* ws = (char*)d_ws;
    size_t off = 0;
    auto alloc = [&](size_t bytes) -> void* {
        void* p = ws + off;
        off += (bytes + 255) & ~(size_t)255;
        return p;
    };
    const int NP = n + 64;  // row padding so GEMM A-frag loads never leave ws
    int*    counts  = (int*)alloc((size_t)(n + 256 * 16) * 4);  // + line-padded bcur
    int*    bcur    = counts + n;
    int*    row_ptr = (int*)alloc((size_t)(n + 1) * 4);
    int*    bsums   = (int*)alloc(256 * 4);
    float*  dinv    = (float*)alloc((size_t)n * 4);
    int2*   binned  = (int2*)alloc((size_t)e * 8);
    int*    csr_src = (int*)alloc((size_t)e * 4);
    float*  csr_w   = (float*)alloc((size_t)e * 4);
    float*  bnscale = (float*)alloc(W0C * 4);
    float*  bnshift = (float*)alloc(W0C * 4);
    __bf16* xb  = (__bf16*)alloc((size_t)NP * IN_C * 2);
    __bf16* w0t = (__bf16*)alloc((size_t)3 * HID * IN_C * 2);
    __bf16* w1t = (__bf16*)alloc((size_t)3 * OUT_C * W0C * 2);
    __bf16* wft = (__bf16*)alloc((size_t)OUT_C * W1C * 2);
    __bf16* t12 = (__bf16*)alloc((size_t)NP * 192 * 2);  // [t1 | t2] hops 1,2 of layer 0
    __bf16* tp  = (__bf16*)alloc((size_t)NP * HID * 2);
    __bf16* h   = (__bf16*)alloc((size_t)NP * W0C * 2);
    __bf16* g   = (__bf16*)alloc((size_t)NP * W1C * 2);
    __bf16* u12 = t12;  // layer-1 [u1 | u2] (n,128) reuses dead t12
    __bf16* up  = tp;   // (n,64) reuses dead tp

    const int TB = 256;
    int nb = (n + 255) / 256;  // 196

    // --- graph prep (src-banded CSR via in-LDS counting sort) ---
    k_zero<<<dim3((n + 256 * 16 + TB - 1) / TB), dim3(TB), 0, stream>>>(counts, n + 256 * 16);
    k_count<<<dim3((e + TB - 1) / TB), dim3(TB), 0, stream>>>(e_col, counts, e);
    k_block_sum<<<dim3(nb), dim3(256), 0, stream>>>(counts, bsums, dinv, n);
    k_scan_bsums<<<dim3(1), dim3(256), 0, stream>>>(bsums, nb);
    k_row_ptr<<<dim3(nb), dim3(256), 0, stream>>>(counts, bsums, row_ptr, n);
    k_binscatter<<<dim3((e + EPB - 1) / EPB), dim3(256), 0, stream>>>(e_row, e_col, row_ptr,
                                                                      bcur, binned, e);
    k_bucket_sort<<<dim3(nb), dim3(256), 0, stream>>>(binned, row_ptr, dinv, csr_src, csr_w, n);
    k_bn_prep<<<dim3(2), dim3(256), 0, stream>>>(bn_g, bn_b, bn_m, bn_v, bnscale, bnshift, W0C);

    // --- dtype prep ---
    k_cvt_bf16<<<dim3((n * IN_C / 8 + TB - 1) / TB), dim3(TB), 0, stream>>>(x, xb, n * IN_C / 8);
    int ttotal = 3 * IN_C * HID + 3 * W0C * OUT_C + W1C * OUT_C;  // 104448
    k_transpose_all<<<dim3((ttotal + TB - 1) / TB), dim3(TB), 0, stream>>>(W0, W1, Wf,
                                                                           w0t, w1t, wft);

    dim3 g64x3((n + 63) / 64, 3);
    dim3 g64((n + 63) / 64);

    // --- layer 0 (hop j = blockIdx.y) ---
    k_mf_l0<<<g64x3, dim3(256), 0, stream>>>(xb, w0t, b0, h, t12, bnscale, bnshift, n);

    // merged SpMM @192ch on t12: first 96 -> h[:,96:192] (BN), second 96 -> tp (raw)
    k_spmm2<24, 12, 8, true, false><<<dim3((n + 7) / 8), dim3(192), 0, stream>>>(
        t12, 192, h + HID, W0C, HID, tp, HID, 0,
        row_ptr, counts, csr_src, csr_w, dinv, n, bnscale, bnshift);
    // second hop: tp -> h[:,192:288] (BN)
    k_spmm<12, 16, true><<<dim3((n + 15) / 16), dim3(192), 0, stream>>>(
        tp, HID, h + 2 * HID, W0C, row_ptr, counts, csr_src, csr_w, dinv, n,
        bnscale, bnshift, 2 * HID);

    // --- layer 1 (hop j = blockIdx.y) ---
    k_mf_l1<<<g64x3, dim3(256), 0, stream>>>(h, w1t, b1, g, u12, n);

    // merged SpMM @128ch on u12: first 64 -> g[:,64:128], second 64 -> up
    k_spmm2<16, 8, 16, false, false><<<dim3((n + 15) / 16), dim3(256), 0, stream>>>(
        u12, 128, g + OUT_C, W1C, 0, up, OUT_C, 0,
        row_ptr, counts, csr_src, csr_w, dinv, n, nullptr, nullptr);
    // second hop: up -> g[:,128:192]
    k_spmm<8, 32, false><<<dim3((n + 31) / 32), dim3(256), 0, stream>>>(
        up, OUT_C, g + 2 * OUT_C, W1C, row_ptr, counts, csr_src, csr_w, dinv, n,
        nullptr, nullptr, 0);

    // --- final projection ---
    k_mf_fin<<<g64, dim3(256), 0, stream>>>(g, wft, bf, out, n);
}

// Round 15
// 362.518 us; speedup vs baseline: 1.1886x; 1.0614x over previous
//
#include <hip/hip_runtime.h>

#define IN_C 128
#define HID 96
#define OUT_C 64
#define W0C 288   // HID*3  (BN width)
#define W1C 192   // OUT_C*3
#define CAP 5120  // per-bucket LDS sort capacity (mean 4096, sigma 64 -> +16 sigma)
#define EPB 4096  // edges per binscatter block

typedef __bf16 bf16x8v __attribute__((ext_vector_type(8)));
typedef float  f32x4v  __attribute__((ext_vector_type(4)));

// ---------------- graph preprocessing ----------------

__global__ void k_zero(int* __restrict__ p, int n) {
    int i = blockIdx.x * blockDim.x + threadIdx.x;
    if (i < n) p[i] = 0;
}

__global__ void k_count(const int* __restrict__ col, int* __restrict__ counts, int e) {
    int i = blockIdx.x * blockDim.x + threadIdx.x;
    if (i < e) atomicAdd(&counts[col[i]], 1);
}

// block sums for bucket scan + dinv (fused: one pass over counts)
__global__ void k_block_sum(const int* __restrict__ counts, int* __restrict__ bsums,
                            float* __restrict__ dinv, int n) {
    __shared__ int s[256];
    int i = blockIdx.x * 256 + threadIdx.x;
    int v = (i < n) ? counts[i] : 0;
    if (i < n) dinv[i] = rsqrtf((float)(v + 1));
    s[threadIdx.x] = v;
    __syncthreads();
    for (int off = 128; off > 0; off >>= 1) {
        if (threadIdx.x < (unsigned)off) s[threadIdx.x] += s[threadIdx.x + off];
        __syncthreads();
    }
    if (threadIdx.x == 0) bsums[blockIdx.x] = s[0];
}

__global__ void k_scan_bsums(int* __restrict__ bsums, int nb) {
    __shared__ int s[256];
    int v = ((int)threadIdx.x < nb) ? bsums[threadIdx.x] : 0;
    s[threadIdx.x] = v;
    __syncthreads();
    for (int off = 1; off < 256; off <<= 1) {
        int t = ((int)threadIdx.x >= off) ? s[threadIdx.x - off] : 0;
        __syncthreads();
        s[threadIdx.x] += t;
        __syncthreads();
    }
    if ((int)threadIdx.x < nb) bsums[threadIdx.x] = s[threadIdx.x] - v;  // exclusive
}

__global__ void k_row_ptr(const int* __restrict__ counts, const int* __restrict__ boffs,
                          int* __restrict__ row_ptr, int n) {
    __shared__ int s[256];
    int i = blockIdx.x * 256 + threadIdx.x;
    int v = (i < n) ? counts[i] : 0;
    s[threadIdx.x] = v;
    __syncthreads();
    for (int off = 1; off < 256; off <<= 1) {
        int t = ((int)threadIdx.x >= off) ? s[threadIdx.x - off] : 0;
        __syncthreads();
        s[threadIdx.x] += t;
        __syncthreads();
    }
    if (i < n) {
        row_ptr[i] = boffs[blockIdx.x] + s[threadIdx.x] - v;
        if (i == n - 1) row_ptr[n] = boffs[blockIdx.x] + s[threadIdx.x];
    }
}

// LDS-aggregated dest-bucket scatter: one global atomic per (block,bucket) on
// line-padded cursors.
__global__ __launch_bounds__(256) void k_binscatter(
        const int* __restrict__ row, const int* __restrict__ col,
        const int* __restrict__ row_ptr, int* __restrict__ bcur /* stride 16 */,
        int2* __restrict__ binned, int e) {
    __shared__ int hist[256];
    __shared__ int base[256];
    int tid = threadIdx.x;
    int e0 = blockIdx.x * EPB;
    int cnt = min(EPB, e - e0);
    hist[tid] = 0;
    __syncthreads();
    int rr[16], cc[16], rk[16];
#pragma unroll
    for (int k = 0; k < 16; k++) {
        int idx = tid + k * 256;
        if (idx < cnt) {
            rr[k] = row[e0 + idx];
            cc[k] = col[e0 + idx];
            rk[k] = atomicAdd(&hist[cc[k] >> 8], 1);
        }
    }
    __syncthreads();
    {
        int h = hist[tid];
        if (h > 0) base[tid] = atomicAdd(&bcur[tid * 16], h);
    }
    __syncthreads();
#pragma unroll
    for (int k = 0; k < 16; k++) {
        int idx = tid + k * 256;
        if (idx < cnt) {
            int b = cc[k] >> 8;
            binned[row_ptr[b << 8] + base[b] + rk[k]] = make_int2(rr[k], cc[k]);
        }
    }
}

// One block per dest bucket; in-LDS src-bucket counting sort then dest-rank
// (R14 form — approximately src-ascending per-dest lists, net-neutral-positive).
__global__ __launch_bounds__(256) void k_bucket_sort(
        const int2* __restrict__ binned, const int* __restrict__ row_ptr,
        const float* __restrict__ dinv,
        int* __restrict__ csr_src, float* __restrict__ csr_w, int n) {
    __shared__ int   s_src[CAP];
    __shared__ int   s_col[CAP];
    __shared__ int   s_ofs[256];
    __shared__ int   lcur[256];
    int tid = threadIdx.x;
    int node0 = blockIdx.x << 8;
    int nodeEnd = min(node0 + 256, n);
    int base = row_ptr[node0];
    int end  = row_ptr[nodeEnd];
    int cnt  = end - base;

    lcur[tid] = 0;
    __syncthreads();
    for (int t = tid; t < cnt; t += 256) {
        atomicAdd(&lcur[binned[base + t].x >> 8], 1);
    }
    __syncthreads();
    {
        int v = lcur[tid];
        s_ofs[tid] = v;
        __syncthreads();
        for (int o = 1; o < 256; o <<= 1) {
            int u = (tid >= o) ? s_ofs[tid - o] : 0;
            __syncthreads();
            s_ofs[tid] += u;
            __syncthreads();
        }
        lcur[tid] = s_ofs[tid] - v;
    }
    __syncthreads();
    for (int t = tid; t < cnt; t += 256) {
        int2 rc = binned[base + t];
        int pos = atomicAdd(&lcur[rc.x >> 8], 1);
        if (pos < CAP) {
            s_src[pos] = rc.x;
            s_col[pos] = rc.y;
        }
    }
    __syncthreads();
    {
        int node = node0 + tid;
        s_ofs[tid] = (node < n) ? (row_ptr[node] - base) : cnt;
        lcur[tid] = 0;
    }
    __syncthreads();
    int lim = min(cnt, CAP);
    for (int t = tid; t < lim; t += 256) {
        int r = s_src[t], c = s_col[t];
        int local = c - node0;
        int pos = s_ofs[local] + atomicAdd(&lcur[local], 1);
        csr_src[base + pos] = r;
        csr_w[base + pos]   = dinv[r] * dinv[c];
    }
}

// ---------------- dtype prep ----------------

__global__ void k_cvt_bf16(const float* __restrict__ src, __bf16* __restrict__ dst, int n8) {
    int i = blockIdx.x * blockDim.x + threadIdx.x;
    if (i >= n8) return;
    bf16x8v o;
#pragma unroll
    for (int q = 0; q < 8; q++) o[q] = (__bf16)src[i * 8 + q];
    *(bf16x8v*)(dst + (size_t)i * 8) = o;
}

// all weight transposes + BN scale/shift in one launch
__global__ void k_prep_all(const float* __restrict__ W0, const float* __restrict__ W1,
                           const float* __restrict__ Wf,
                           const float* __restrict__ gamma, const float* __restrict__ beta,
                           const float* __restrict__ mean, const float* __restrict__ var,
                           __bf16* __restrict__ w0t, __bf16* __restrict__ w1t,
                           __bf16* __restrict__ wft,
                           float* __restrict__ scale, float* __restrict__ shift) {
    const int T0 = 3 * IN_C * HID;    // 36864
    const int T1 = 3 * W0C * OUT_C;   // 55296
    const int T2 = W1C * OUT_C;       // 12288
    int i = blockIdx.x * blockDim.x + threadIdx.x;
    if (i < T0) {
        int kn = IN_C * HID;
        int j = i / kn, r = i % kn;
        int k = r / HID, nn = r % HID;
        w0t[(size_t)j * kn + (size_t)nn * IN_C + k] = (__bf16)W0[i];
    } else if (i < T0 + T1) {
        int ii = i - T0;
        int kn = W0C * OUT_C;
        int j = ii / kn, r = ii % kn;
        int k = r / OUT_C, nn = r % OUT_C;
        w1t[(size_t)j * kn + (size_t)nn * W0C + k] = (__bf16)W1[ii];
    } else if (i < T0 + T1 + T2) {
        int ii = i - T0 - T1;
        int k = ii / OUT_C, nn = ii % OUT_C;
        wft[(size_t)nn * W1C + k] = (__bf16)Wf[ii];
    } else if (i < T0 + T1 + T2 + W0C) {
        int ii = i - T0 - T1 - T2;
        float s = gamma[ii] * rsqrtf(var[ii] + 1e-5f);
        scale[ii] = s;
        shift[ii] = beta[ii] - mean[ii] * s;
    }
}

// ---------------- MFMA GEMMs (hop j = blockIdx.y; BM=128, 2 row-tiles/wave) -------
// A-frag: m = lane&15, k = quad*8+j ; B-frag: n = lane&15, k = quad*8+j (WT = (N,K))
// D: col = lane&15, row = quad*4 + reg. Two independent A-streams per wave double
// the loads in flight and the MFMA work per B-load (B reused across tiles).
// Epilogues repack D through a padded LDS tile -> coalesced vector stores.

// layer 0: xb (M,128) @ W0[j]; j0: BN+ReLU -> h[:,0:96] (ld 288); j1/j2 -> t12 (ld 192)
__global__ __launch_bounds__(256) void k_mf_l0(
        const __bf16* __restrict__ xb, const __bf16* __restrict__ w0t /* (3,96,128) */,
        const float* __restrict__ bias /* (3,96) */,
        __bf16* __restrict__ h, __bf16* __restrict__ t12,
        const float* __restrict__ scale, const float* __restrict__ shift, int M) {
    const int RS = 104;
    __shared__ __bf16 tile[128 * RS];   // 26.6 KB
    int tid = threadIdx.x;
    int wave = tid >> 6, lane = tid & 63;
    int ln = lane & 15, quad = lane >> 4;
    int j = blockIdx.y;
    int rowBase = blockIdx.x * 128;
    int waveRow = wave * 16;
    const __bf16* wjt = w0t + (size_t)j * HID * IN_C;
    f32x4v acc[2][6];
#pragma unroll
    for (int u = 0; u < 2; u++)
#pragma unroll
        for (int t = 0; t < 6; t++) acc[u][t] = (f32x4v){0.f, 0.f, 0.f, 0.f};
    const __bf16* arow0 = xb + (size_t)(rowBase + waveRow + ln) * IN_C + quad * 8;
    const __bf16* arow1 = arow0 + (size_t)64 * IN_C;
#pragma unroll
    for (int k = 0; k < 4; k++) {
        bf16x8v a0 = *(const bf16x8v*)(arow0 + k * 32);
        bf16x8v a1 = *(const bf16x8v*)(arow1 + k * 32);
#pragma unroll
        for (int c = 0; c < 6; c++) {
            bf16x8v b = *(const bf16x8v*)(wjt + (size_t)(c * 16 + ln) * IN_C + k * 32 + quad * 8);
            acc[0][c] = __builtin_amdgcn_mfma_f32_16x16x32_bf16(a0, b, acc[0][c], 0, 0, 0);
            acc[1][c] = __builtin_amdgcn_mfma_f32_16x16x32_bf16(a1, b, acc[1][c], 0, 0, 0);
        }
    }
    const float* bj = bias + j * HID;
    bool bn = (j == 0);
#pragma unroll
    for (int u = 0; u < 2; u++)
#pragma unroll
        for (int r = 0; r < 4; r++) {
            int lr = u * 64 + waveRow + quad * 4 + r;
#pragma unroll
            for (int c = 0; c < 6; c++) {
                int col = c * 16 + ln;
                float v = acc[u][c][r] + bj[col];
                if (bn) v = fmaxf(v * scale[col] + shift[col], 0.f);
                tile[lr * RS + col] = (__bf16)v;
            }
        }
    __syncthreads();
    __bf16* dst; int ld, c0;
    if (j == 0) { dst = h;   ld = W0C; c0 = 0; }
    else        { dst = t12; ld = 192; c0 = (j - 1) * 96; }
#pragma unroll
    for (int s = 0; s < 6; s++) {
        int idx = tid + s * 256;          // 128 rows * 12 chunks
        int r = idx / 12, c8 = idx % 12;
        int grow = rowBase + r;
        if (grow < M)
            *(bf16x8v*)(dst + (size_t)grow * ld + c0 + c8 * 8) =
                *(const bf16x8v*)(tile + r * RS + c8 * 8);
    }
}

// layer 1 (hop-split): h (M,288) @ W1[j]; j0 -> g[:,0:64]; j1/j2 -> u12
__global__ __launch_bounds__(256) void k_mf_l1(
        const __bf16* __restrict__ hb, const __bf16* __restrict__ w1t /* (3,64,288) */,
        const float* __restrict__ bias /* (3,64) */,
        __bf16* __restrict__ g, __bf16* __restrict__ u12, int M) {
    const int RS = 72;
    __shared__ __bf16 tile[128 * RS];   // 18.4 KB
    int tid = threadIdx.x;
    int wave = tid >> 6, lane = tid & 63;
    int ln = lane & 15, quad = lane >> 4;
    int j = blockIdx.y;
    int rowBase = blockIdx.x * 128;
    int waveRow = wave * 16;
    const __bf16* wjt = w1t + (size_t)j * OUT_C * W0C;
    f32x4v acc[2][4];
#pragma unroll
    for (int u = 0; u < 2; u++)
#pragma unroll
        for (int t = 0; t < 4; t++) acc[u][t] = (f32x4v){0.f, 0.f, 0.f, 0.f};
    const __bf16* arow0 = hb + (size_t)(rowBase + waveRow + ln) * W0C + quad * 8;
    const __bf16* arow1 = arow0 + (size_t)64 * W0C;
#pragma unroll
    for (int k = 0; k < 9; k++) {
        bf16x8v a0 = *(const bf16x8v*)(arow0 + k * 32);
        bf16x8v a1 = *(const bf16x8v*)(arow1 + k * 32);
#pragma unroll
        for (int c = 0; c < 4; c++) {
            bf16x8v b = *(const bf16x8v*)(wjt + (size_t)(c * 16 + ln) * W0C + k * 32 + quad * 8);
            acc[0][c] = __builtin_amdgcn_mfma_f32_16x16x32_bf16(a0, b, acc[0][c], 0, 0, 0);
            acc[1][c] = __builtin_amdgcn_mfma_f32_16x16x32_bf16(a1, b, acc[1][c], 0, 0, 0);
        }
    }
    const float* bj = bias + j * OUT_C;
#pragma unroll
    for (int u = 0; u < 2; u++)
#pragma unroll
        for (int r = 0; r < 4; r++) {
            int lr = u * 64 + waveRow + quad * 4 + r;
#pragma unroll
            for (int c = 0; c < 4; c++) {
                int col = c * 16 + ln;
                tile[lr * RS + col] = (__bf16)(acc[u][c][r] + bj[col]);
            }
        }
    __syncthreads();
    __bf16* dst; int ld, c0;
    if (j == 0) { dst = g;   ld = W1C; c0 = 0; }
    else        { dst = u12; ld = 128; c0 = (j - 1) * 64; }
#pragma unroll
    for (int s = 0; s < 4; s++) {
        int idx = tid + s * 256;          // 128 rows * 8 chunks
        int r = idx / 8, c8 = idx % 8;
        int grow = rowBase + r;
        if (grow < M)
            *(bf16x8v*)(dst + (size_t)grow * ld + c0 + c8 * 8) =
                *(const bf16x8v*)(tile + r * RS + c8 * 8);
    }
}

// final: g (M,192) @ Wf -> out fp32 (M,64)
__global__ __launch_bounds__(256) void k_mf_fin(
        const __bf16* __restrict__ gb, const __bf16* __restrict__ wft /* (64,192) */,
        const float* __restrict__ bias, float* __restrict__ out, int M) {
    const int RS = 68;
    __shared__ float tile[128 * RS];    // 34.8 KB
    int tid = threadIdx.x;
    int wave = tid >> 6, lane = tid & 63;
    int ln = lane & 15, quad = lane >> 4;
    int rowBase = blockIdx.x * 128;
    int waveRow = wave * 16;
    f32x4v acc[2][4];
#pragma unroll
    for (int u = 0; u < 2; u++)
#pragma unroll
        for (int t = 0; t < 4; t++) acc[u][t] = (f32x4v){0.f, 0.f, 0.f, 0.f};
    const __bf16* arow0 = gb + (size_t)(rowBase + waveRow + ln) * W1C + quad * 8;
    const __bf16* arow1 = arow0 + (size_t)64 * W1C;
#pragma unroll
    for (int k = 0; k < 6; k++) {
        bf16x8v a0 = *(const bf16x8v*)(arow0 + k * 32);
        bf16x8v a1 = *(const bf16x8v*)(arow1 + k * 32);
#pragma unroll
        for (int c = 0; c < 4; c++) {
            bf16x8v b = *(const bf16x8v*)(wft + (size_t)(c * 16 + ln) * W1C + k * 32 + quad * 8);
            acc[0][c] = __builtin_amdgcn_mfma_f32_16x16x32_bf16(a0, b, acc[0][c], 0, 0, 0);
            acc[1][c] = __builtin_amdgcn_mfma_f32_16x16x32_bf16(a1, b, acc[1][c], 0, 0, 0);
        }
    }
#pragma unroll
    for (int u = 0; u < 2; u++)
#pragma unroll
        for (int r = 0; r < 4; r++) {
            int lr = u * 64 + waveRow + quad * 4 + r;
#pragma unroll
            for (int c = 0; c < 4; c++) {
                int col = c * 16 + ln;
                tile[lr * RS + col] = acc[u][c][r] + bias[col];
            }
        }
    __syncthreads();
#pragma unroll
    for (int s = 0; s < 8; s++) {
        int idx = tid + s * 256;          // 128 rows * 16 float4-chunks
        int r = idx / 16, c4 = idx % 16;
        int grow = rowBase + r;
        if (grow < M)
            *(float4*)(out + (size_t)grow * OUT_C + c4 * 4) =
                *(const float4*)(tile + r * RS + c4 * 4);
    }
}

// ---------------- SpMM bf16 (CSR gather, no atomics, 4x-unrolled MLP) -------------
// (4x is the measured optimum: 8x costs occupancy and regresses — R11)
template <int C8, int NPB, bool BNRELU>
__global__ void k_spmm(const __bf16* __restrict__ xin, int ldx,
                       __bf16* __restrict__ xout, int ldo,
                       const int* __restrict__ row_ptr, const int* __restrict__ counts,
                       const int* __restrict__ csr_src, const float* __restrict__ csr_w,
                       const float* __restrict__ dinv, int n,
                       const float* __restrict__ scale, const float* __restrict__ shift,
                       int chan0) {
    int c8 = threadIdx.x % C8;
    int nl = threadIdx.x / C8;
    int node = blockIdx.x * NPB + nl;
    if (node >= n) return;
    float di = dinv[node];
    float lw = di * di;
    float acc[8];
    {
        bf16x8v v = *(const bf16x8v*)(xin + (size_t)node * ldx + c8 * 8);
#pragma unroll
        for (int q = 0; q < 8; q++) acc[q] = lw * (float)v[q];
    }
    int start = row_ptr[node];
    int cnt = counts[node];
    int k = 0;
    for (; k + 4 <= cnt; k += 4) {
        int s0 = csr_src[start + k + 0], s1 = csr_src[start + k + 1];
        int s2 = csr_src[start + k + 2], s3 = csr_src[start + k + 3];
        float w0 = csr_w[start + k + 0], w1 = csr_w[start + k + 1];
        float w2 = csr_w[start + k + 2], w3 = csr_w[start + k + 3];
        bf16x8v v0 = *(const bf16x8v*)(xin + (size_t)s0 * ldx + c8 * 8);
        bf16x8v v1 = *(const bf16x8v*)(xin + (size_t)s1 * ldx + c8 * 8);
        bf16x8v v2 = *(const bf16x8v*)(xin + (size_t)s2 * ldx + c8 * 8);
        bf16x8v v3 = *(const bf16x8v*)(xin + (size_t)s3 * ldx + c8 * 8);
#pragma unroll
        for (int q = 0; q < 8; q++)
            acc[q] += w0 * (float)v0[q] + w1 * (float)v1[q] +
                      w2 * (float)v2[q] + w3 * (float)v3[q];
    }
    for (; k < cnt; k++) {
        int src = csr_src[start + k];
        float w = csr_w[start + k];
        bf16x8v xv = *(const bf16x8v*)(xin + (size_t)src * ldx + c8 * 8);
#pragma unroll
        for (int q = 0; q < 8; q++) acc[q] += w * (float)xv[q];
    }
    bf16x8v o;
#pragma unroll
    for (int q = 0; q < 8; q++) {
        float v = acc[q];
        if (BNRELU) {
            int ch = chan0 + c8 * 8 + q;
            v = fmaxf(v * scale[ch] + shift[ch], 0.f);
        }
        o[q] = (__bf16)v;
    }
    *(bf16x8v*)(xout + (size_t)node * ldo + c8 * 8) = o;
}

template <int C8, int SPLIT, int NPB, bool BNA, bool BNB>
__global__ void k_spmm2(const __bf16* __restrict__ xin, int ldx,
                        __bf16* __restrict__ dstA, int ldA, int chanA,
                        __bf16* __restrict__ dstB, int ldB, int chanB,
                        const int* __restrict__ row_ptr, const int* __restrict__ counts,
                        const int* __restrict__ csr_src, const float* __restrict__ csr_w,
                        const float* __restrict__ dinv, int n,
                        const float* __restrict__ scale, const float* __restrict__ shift) {
    int c8 = threadIdx.x % C8;
    int nl = threadIdx.x / C8;
    int node = blockIdx.x * NPB + nl;
    if (node >= n) return;
    float di = dinv[node];
    float lw = di * di;
    float acc[8];
    {
        bf16x8v v = *(const bf16x8v*)(xin + (size_t)node * ldx + c8 * 8);
#pragma unroll
        for (int q = 0; q < 8; q++) acc[q] = lw * (float)v[q];
    }
    int start = row_ptr[node];
    int cnt = counts[node];
    int k = 0;
    for (; k + 4 <= cnt; k += 4) {
        int s0 = csr_src[start + k + 0], s1 = csr_src[start + k + 1];
        int s2 = csr_src[start + k + 2], s3 = csr_src[start + k + 3];
        float w0 = csr_w[start + k + 0], w1 = csr_w[start + k + 1];
        float w2 = csr_w[start + k + 2], w3 = csr_w[start + k + 3];
        bf16x8v v0 = *(const bf16x8v*)(xin + (size_t)s0 * ldx + c8 * 8);
        bf16x8v v1 = *(const bf16x8v*)(xin + (size_t)s1 * ldx + c8 * 8);
        bf16x8v v2 = *(const bf16x8v*)(xin + (size_t)s2 * ldx + c8 * 8);
        bf16x8v v3 = *(const bf16x8v*)(xin + (size_t)s3 * ldx + c8 * 8);
#pragma unroll
        for (int q = 0; q < 8; q++)
            acc[q] += w0 * (float)v0[q] + w1 * (float)v1[q] +
                      w2 * (float)v2[q] + w3 * (float)v3[q];
    }
    for (; k < cnt; k++) {
        int src = csr_src[start + k];
        float w = csr_w[start + k];
        bf16x8v xv = *(const bf16x8v*)(xin + (size_t)src * ldx + c8 * 8);
#pragma unroll
        for (int q = 0; q < 8; q++) acc[q] += w * (float)xv[q];
    }
    bool isA = c8 < SPLIT;
    __bf16* dst = isA ? dstA : dstB;
    int ld   = isA ? ldA : ldB;
    int lc8  = isA ? c8 : c8 - SPLIT;
    int chan = isA ? chanA : chanB;
    bool bn  = isA ? BNA : BNB;
    bf16x8v o;
#pragma unroll
    for (int q = 0; q < 8; q++) {
        float v = acc[q];
        if (bn) {
            int ch = chan + lc8 * 8 + q;
            v = fmaxf(v * scale[ch] + shift[ch], 0.f);
        }
        o[q] = (__bf16)v;
    }
    *(bf16x8v*)(dst + (size_t)node * ld + lc8 * 8) = o;
}

// ---------------- launch ----------------

extern "C" void kernel_launch(void* const* d_in, const int* in_sizes, int n_in,
                              void* d_out, int out_size, void* d_ws, size_t ws_size,
                              hipStream_t stream) {
    const int n = in_sizes[0] / IN_C;   // 50000
    const int e = in_sizes[1] / 2;      // 800000

    const float* x    = (const float*)d_in[0];
    const int*   ei   = (const int*)d_in[1];
    const float* W0   = (const float*)d_in[2];   // (3,128,96)
    const float* b0   = (const float*)d_in[3];
    const float* W1   = (const float*)d_in[4];   // (3,288,64)
    const float* b1   = (const float*)d_in[5];
    const float* bn_g = (const float*)d_in[6];
    const float* bn_b = (const float*)d_in[7];
    const float* bn_m = (const float*)d_in[8];
    const float* bn_v = (const float*)d_in[9];
    const float* Wf   = (const float*)d_in[10];  // (192,64)
    const float* bf   = (const float*)d_in[11];
    float* out = (float*)d_out;

    const int* e_row = ei;
    const int* e_col = ei + e;

    char* ws = (char*)d_ws;
    size_t off = 0;
    auto alloc = [&](size_t bytes) -> void* {
        void* p = ws + off;
        off += (bytes + 255) & ~(size_t)255;
        return p;
    };
    const int NP = n + 128;  // row padding so GEMM A-frag loads never leave ws (BM=128)
    int*    counts  = (int*)alloc((size_t)(n + 256 * 16) * 4);  // + line-padded bcur
    int*    bcur    = counts + n;
    int*    row_ptr = (int*)alloc((size_t)(n + 1) * 4);
    int*    bsums   = (int*)alloc(256 * 4);
    float*  dinv    = (float*)alloc((size_t)n * 4);
    int2*   binned  = (int2*)alloc((size_t)e * 8);
    int*    csr_src = (int*)alloc((size_t)e * 4);
    float*  csr_w   = (float*)alloc((size_t)e * 4);
    float*  bnscale = (float*)alloc(W0C * 4);
    float*  bnshift = (float*)alloc(W0C * 4);
    __bf16* xb  = (__bf16*)alloc((size_t)NP * IN_C * 2);
    __bf16* w0t = (__bf16*)alloc((size_t)3 * HID * IN_C * 2);
    __bf16* w1t = (__bf16*)alloc((size_t)3 * OUT_C * W0C * 2);
    __bf16* wft = (__bf16*)alloc((size_t)OUT_C * W1C * 2);
    __bf16* t12 = (__bf16*)alloc((size_t)NP * 192 * 2);  // [t1 | t2] hops 1,2 of layer 0
    __bf16* tp  = (__bf16*)alloc((size_t)NP * HID * 2);
    __bf16* h   = (__bf16*)alloc((size_t)NP * W0C * 2);
    __bf16* g   = (__bf16*)alloc((size_t)NP * W1C * 2);
    __bf16* u12 = t12;  // layer-1 [u1 | u2] (n,128) reuses dead t12
    __bf16* up  = tp;   // (n,64) reuses dead tp

    const int TB = 256;
    int nb = (n + 255) / 256;  // 196

    // --- graph prep ---
    k_zero<<<dim3((n + 256 * 16 + TB - 1) / TB), dim3(TB), 0, stream>>>(counts, n + 256 * 16);
    k_count<<<dim3((e + TB - 1) / TB), dim3(TB), 0, stream>>>(e_col, counts, e);
    k_block_sum<<<dim3(nb), dim3(256), 0, stream>>>(counts, bsums, dinv, n);
    k_scan_bsums<<<dim3(1), dim3(256), 0, stream>>>(bsums, nb);
    k_row_ptr<<<dim3(nb), dim3(256), 0, stream>>>(counts, bsums, row_ptr, n);
    k_binscatter<<<dim3((e + EPB - 1) / EPB), dim3(256), 0, stream>>>(e_row, e_col, row_ptr,
                                                                      bcur, binned, e);
    k_bucket_sort<<<dim3(nb), dim3(256), 0, stream>>>(binned, row_ptr, dinv, csr_src, csr_w, n);

    // --- dtype prep (weights + BN in one launch) ---
    k_cvt_bf16<<<dim3((n * IN_C / 8 + TB - 1) / TB), dim3(TB), 0, stream>>>(x, xb, n * IN_C / 8);
    int ptotal = 3 * IN_C * HID + 3 * W0C * OUT_C + W1C * OUT_C + W0C;
    k_prep_all<<<dim3((ptotal + TB - 1) / TB), dim3(TB), 0, stream>>>(
        W0, W1, Wf, bn_g, bn_b, bn_m, bn_v, w0t, w1t, wft, bnscale, bnshift);

    dim3 g128x3((n + 127) / 128, 3);
    dim3 g128((n + 127) / 128);

    // --- layer 0 (hop j = blockIdx.y, BM=128) ---
    k_mf_l0<<<g128x3, dim3(256), 0, stream>>>(xb, w0t, b0, h, t12, bnscale, bnshift, n);

    // merged SpMM @192ch on t12: first 96 -> h[:,96:192] (BN), second 96 -> tp (raw)
    k_spmm2<24, 12, 8, true, false><<<dim3((n + 7) / 8), dim3(192), 0, stream>>>(
        t12, 192, h + HID, W0C, HID, tp, HID, 0,
        row_ptr, counts, csr_src, csr_w, dinv, n, bnscale, bnshift);
    // second hop: tp -> h[:,192:288] (BN)
    k_spmm<12, 16, true><<<dim3((n + 15) / 16), dim3(192), 0, stream>>>(
        tp, HID, h + 2 * HID, W0C, row_ptr, counts, csr_src, csr_w, dinv, n,
        bnscale, bnshift, 2 * HID);

    // --- layer 1 (hop j = blockIdx.y, BM=128) ---
    k_mf_l1<<<g128x3, dim3(256), 0, stream>>>(h, w1t, b1, g, u12, n);

    // merged SpMM @128ch on u12: first 64 -> g[:,64:128], second 64 -> up
    k_spmm2<16, 8, 16, false, false><<<dim3((n + 15) / 16), dim3(256), 0, stream>>>(
        u12, 128, g + OUT_C, W1C, 0, up, OUT_C, 0,
        row_ptr, counts, csr_src, csr_w, dinv, n, nullptr, nullptr);
    // second hop: up -> g[:,128:192]
    k_spmm<8, 32, false><<<dim3((n + 31) / 32), dim3(256), 0, stream>>>(
        up, OUT_C, g + 2 * OUT_C, W1C, row_ptr, counts, csr_src, csr_w, dinv, n,
        nullptr, nullptr, 0);

    // --- final projection (BM=128) ---
    k_mf_fin<<<g128, dim3(256), 0, stream>>>(g, wft, bf, out, n);
}